// Round 13
// baseline (104.578 us; speedup 1.0000x reference)
//
#include <hip/hip_runtime.h>
#include <hip/hip_bf16.h>

#define BATCH 262144
#define NSITES 64
#define NJ 4                    // j-tiles per wave (64 batch elems/wave)
#define BLOCK_BATCH 256         // batch elems per 256-thread block

typedef __attribute__((ext_vector_type(8))) short short8;
typedef __attribute__((ext_vector_type(4))) float f32x4;

__device__ __forceinline__ unsigned cvt_pk_bf16(float a, float b) {
  unsigned r;
  asm("v_cvt_pk_bf16_f32 %0, %1, %2" : "=v"(r) : "v"(a), "v"(b));
  return r;
}

// slot k = [k4 k3 | k2 k1 k0] -> logical chi = 16*k2 + 4*(k4k3) + (k1k0)
__device__ __forceinline__ int qmap(int k) {
  return (((k >> 2) & 1) << 4) | (((k >> 3) & 3) << 2) | (k & 3);
}

// pack: element idx = ((p*4 + f)*64 + l)*8 + t   (chunk = 16B = 8 bf16)
// f = m*2 + h ; l = g*16 + col ; value = bf16(cores[p][qmap(8g+t)][m][h*16+col] - delta)
// step s (1..63) reads panel p = s-1 at byte offset p*4096 + f*1024 + l*16.
__global__ void pack_E(const float* __restrict__ cores, unsigned short* __restrict__ Ep) {
  int idx = blockIdx.x * 256 + threadIdx.x;
  if (idx >= (NSITES - 1) * 2048) return;
  int t = idx & 7;
  int l = (idx >> 3) & 63;
  int f = (idx >> 9) & 3;
  int p = idx >> 11;
  int g = l >> 4, col = l & 15;
  int m = f >> 1, h = f & 1;
  int k = 8 * g + t, c = h * 16 + col;
  int b = qmap(k);
  float val = cores[((p * 32 + b) * 2 + m) * 32 + c] - ((b == c) ? 1.0f : 0.0f);
  __hip_bfloat16 hv = __float2bfloat16(val);
  Ep[idx] = *(unsigned short*)&hv;
}

#define BODYJ(jj, xx0, xx1)                                                     \
  {                                                                             \
    union { short8 s8; unsigned u[4]; } vb;                                     \
    vb.u[0] = cvt_pk_bf16(v[jj][0], v[jj][1]);                                  \
    vb.u[1] = cvt_pk_bf16(v[jj][2], v[jj][3]);                                  \
    vb.u[2] = cvt_pk_bf16(v[jj][4], v[jj][5]);                                  \
    vb.u[3] = cvt_pk_bf16(v[jj][6], v[jj][7]);                                  \
    const f32x4 z = {0.f, 0.f, 0.f, 0.f};                                       \
    f32x4 r0lo = __builtin_amdgcn_mfma_f32_16x16x32_bf16(A0, vb.s8, z, 0, 0, 0); \
    f32x4 r0hi = __builtin_amdgcn_mfma_f32_16x16x32_bf16(A1, vb.s8, z, 0, 0, 0); \
    f32x4 r1lo = __builtin_amdgcn_mfma_f32_16x16x32_bf16(A2, vb.s8, z, 0, 0, 0); \
    f32x4 r1hi = __builtin_amdgcn_mfma_f32_16x16x32_bf16(A3, vb.s8, z, 0, 0, 0); \
    const float ss = (xx0) + (xx1);                                             \
    _Pragma("unroll") for (int t = 0; t < 4; ++t) {                             \
      v[jj][t] = ss * v[jj][t] + (xx0)*r0lo[t] + (xx1)*r1lo[t];                 \
      v[jj][4 + t] = ss * v[jj][4 + t] + (xx0)*r0hi[t] + (xx1)*r1hi[t];         \
    }                                                                           \
  }

__global__ __launch_bounds__(256, 4) void mps_chain_kernel(
    const float* __restrict__ X, const float* __restrict__ core0,
    const float* __restrict__ coreN, const unsigned short* __restrict__ Ep,
    float* __restrict__ out) {
  const int tid = threadIdx.x;
  const int lane = tid & 63;
  const int wave = tid >> 6;
  const int col = lane & 15;  // batch column within 16-wide tile
  const int g = lane >> 4;    // k-group (slots 8g..8g+7)
  const int abase = blockIdx.x * BLOCK_BATCH + wave * (16 * NJ);

  // ---- v0 = X[0] @ core0 ----
  float c0[2][8];
#pragma unroll
  for (int m = 0; m < 2; ++m)
#pragma unroll
    for (int t = 0; t < 8; ++t) c0[m][t] = core0[m * 32 + qmap(8 * g + t)];

  float v[NJ][8];
#pragma unroll
  for (int jj = 0; jj < NJ; ++jj) {
    const float2 xj = *(const float2*)(X + 2 * (size_t)(abase + jj * 16 + col));
#pragma unroll
    for (int t = 0; t < 8; ++t) v[jj][t] = xj.x * c0[0][t] + xj.y * c0[1][t];
  }

  // ---- main chain: NO barriers, NO LDS, all loads at-use ----
  // E fragments from L1 (panel shared by all waves on the CU);
  // X streamed from HBM/L2; waves run unsynchronized and self-stagger.
  const char* ep_base = (const char*)Ep + (size_t)lane * 16;
  const float* xs = X + 2 * ((size_t)BATCH + abase + col);

#pragma unroll 1
  for (int s = 1; s < NSITES; ++s) {
    const short8* ep = (const short8*)ep_base;
    const short8 A0 = ep[0], A1 = ep[64], A2 = ep[128], A3 = ep[192];

    float2 xj[NJ];
#pragma unroll
    for (int jj = 0; jj < NJ; ++jj)
      xj[jj] = *(const float2*)(xs + 2 * (jj * 16));

    BODYJ(0, xj[0].x, xj[0].y);
    BODYJ(1, xj[1].x, xj[1].y);
    BODYJ(2, xj[2].x, xj[2].y);
    BODYJ(3, xj[3].x, xj[3].y);

    ep_base += 4096;
    xs += 2 * (size_t)BATCH;
  }

  // ---- epilogue: out = |v @ coreN| ----
  float cN[8][2];
#pragma unroll
  for (int t = 0; t < 8; ++t) {
    cN[t][0] = coreN[qmap(8 * g + t) * 2 + 0];
    cN[t][1] = coreN[qmap(8 * g + t) * 2 + 1];
  }
#pragma unroll
  for (int jj = 0; jj < NJ; ++jj) {
    float p0 = 0.f, p1 = 0.f;
#pragma unroll
    for (int t = 0; t < 8; ++t) {
      p0 += v[jj][t] * cN[t][0];
      p1 += v[jj][t] * cN[t][1];
    }
    p0 += __shfl_xor(p0, 16);
    p0 += __shfl_xor(p0, 32);
    p1 += __shfl_xor(p1, 16);
    p1 += __shfl_xor(p1, 32);
    if (g == 0) {
      const int a = abase + jj * 16 + col;
      out[2 * a] = fabsf(p0);
      out[2 * a + 1] = fabsf(p1);
    }
  }
}

extern "C" void kernel_launch(void* const* d_in, const int* in_sizes, int n_in,
                              void* d_out, int out_size, void* d_ws, size_t ws_size,
                              hipStream_t stream) {
  const float* X = (const float*)d_in[0];
  const float* core0 = (const float*)d_in[1];
  const float* cores = (const float*)d_in[2];
  const float* coreN = (const float*)d_in[3];
  float* out = (float*)d_out;
  unsigned short* Ep = (unsigned short*)d_ws;  // 258048 bytes

  hipLaunchKernelGGL(pack_E, dim3(((NSITES - 1) * 2048 + 255) / 256), dim3(256), 0, stream,
                     cores, Ep);
  hipLaunchKernelGGL(mps_chain_kernel, dim3(BATCH / BLOCK_BATCH), dim3(256), 0, stream, X,
                     core0, coreN, Ep, out);
}

// Round 14
// 99.747 us; speedup vs baseline: 1.0484x; 1.0484x over previous
//
#include <hip/hip_runtime.h>
#include <hip/hip_bf16.h>

#define BATCH 262144
#define NSITES 64
#define NJ 4                    // j-tiles per wave (64 batch elems/wave)
#define BLOCK_BATCH 256         // batch elems per 256-thread block

typedef __attribute__((ext_vector_type(8))) short short8;
typedef __attribute__((ext_vector_type(4))) float f32x4;

// slot k = [k4 k3 | k2 k1 k0] -> logical chi = 16*k2 + 4*(k4k3) + (k1k0)
__device__ __forceinline__ int qmap(int k) {
  return (((k >> 2) & 1) << 4) | (((k >> 3) & 3) << 2) | (k & 3);
}

// pack: element idx = ((p*4 + f)*64 + l)*8 + t   (chunk = 16B = 8 bf16)
// f = m*2 + h ; l = g*16 + col ; value = bf16(cores[p][qmap(8g+t)][m][h*16+col] - delta)
// step s (1..63) reads panel p = s-1 at byte offset p*4096 + f*1024 + l*16.
__global__ void pack_E(const float* __restrict__ cores, unsigned short* __restrict__ Ep) {
  int idx = blockIdx.x * 256 + threadIdx.x;
  if (idx >= (NSITES - 1) * 2048) return;
  int t = idx & 7;
  int l = (idx >> 3) & 63;
  int f = (idx >> 9) & 3;
  int p = idx >> 11;
  int g = l >> 4, col = l & 15;
  int m = f >> 1, h = f & 1;
  int k = 8 * g + t, c = h * 16 + col;
  int b = qmap(k);
  float val = cores[((p * 32 + b) * 2 + m) * 32 + c] - ((b == c) ? 1.0f : 0.0f);
  __hip_bfloat16 hv = __float2bfloat16(val);
  Ep[idx] = *(unsigned short*)&hv;
}

#define BODYJ(jj, xx0, xx1)                                                     \
  {                                                                             \
    union { short8 s8; __hip_bfloat162 h2[4]; } vb;                             \
    vb.h2[0] = __float22bfloat162_rn(make_float2(v[jj][0], v[jj][1]));          \
    vb.h2[1] = __float22bfloat162_rn(make_float2(v[jj][2], v[jj][3]));          \
    vb.h2[2] = __float22bfloat162_rn(make_float2(v[jj][4], v[jj][5]));          \
    vb.h2[3] = __float22bfloat162_rn(make_float2(v[jj][6], v[jj][7]));          \
    const f32x4 z = {0.f, 0.f, 0.f, 0.f};                                       \
    __builtin_amdgcn_s_setprio(1);                                              \
    f32x4 r0lo = __builtin_amdgcn_mfma_f32_16x16x32_bf16(A0, vb.s8, z, 0, 0, 0); \
    f32x4 r0hi = __builtin_amdgcn_mfma_f32_16x16x32_bf16(A1, vb.s8, z, 0, 0, 0); \
    f32x4 r1lo = __builtin_amdgcn_mfma_f32_16x16x32_bf16(A2, vb.s8, z, 0, 0, 0); \
    f32x4 r1hi = __builtin_amdgcn_mfma_f32_16x16x32_bf16(A3, vb.s8, z, 0, 0, 0); \
    __builtin_amdgcn_s_setprio(0);                                              \
    const float ss = (xx0) + (xx1);                                             \
    _Pragma("unroll") for (int t = 0; t < 4; ++t) {                             \
      v[jj][t] = ss * v[jj][t] + (xx0)*r0lo[t] + (xx1)*r1lo[t];                 \
      v[jj][4 + t] = ss * v[jj][4 + t] + (xx0)*r0hi[t] + (xx1)*r1hi[t];         \
    }                                                                           \
  }

__global__ __launch_bounds__(256, 4) void mps_chain_kernel(
    const float* __restrict__ X, const float* __restrict__ core0,
    const float* __restrict__ coreN, const unsigned short* __restrict__ Ep,
    float* __restrict__ out) {
  const int tid = threadIdx.x;
  const int lane = tid & 63;
  const int wave = tid >> 6;
  const int col = lane & 15;  // batch column within 16-wide tile
  const int g = lane >> 4;    // k-group (slots 8g..8g+7)
  const int abase = blockIdx.x * BLOCK_BATCH + wave * (16 * NJ);

  // ---- v0 = X[0] @ core0 ----
  float c0[2][8];
#pragma unroll
  for (int m = 0; m < 2; ++m)
#pragma unroll
    for (int t = 0; t < 8; ++t) c0[m][t] = core0[m * 32 + qmap(8 * g + t)];

  float v[NJ][8];
#pragma unroll
  for (int jj = 0; jj < NJ; ++jj) {
    const float2 xj = *(const float2*)(X + 2 * (size_t)(abase + jj * 16 + col));
#pragma unroll
    for (int t = 0; t < 8; ++t) v[jj][t] = xj.x * c0[0][t] + xj.y * c0[1][t];
  }

  // ---- main chain: NO barriers, NO LDS, all loads at-use ----
  // E fragments from L1 (panel shared by all waves on the CU);
  // X streamed from HBM/L2; waves run unsynchronized and self-stagger.
  const char* ep_base = (const char*)Ep + (size_t)lane * 16;
  const float* xs = X + 2 * ((size_t)BATCH + abase + col);

#pragma unroll 1
  for (int s = 1; s < NSITES; ++s) {
    const short8* ep = (const short8*)ep_base;
    const short8 A0 = ep[0], A1 = ep[64], A2 = ep[128], A3 = ep[192];

    float2 xj[NJ];
#pragma unroll
    for (int jj = 0; jj < NJ; ++jj)
      xj[jj] = *(const float2*)(xs + 2 * (jj * 16));

    BODYJ(0, xj[0].x, xj[0].y);
    BODYJ(1, xj[1].x, xj[1].y);
    BODYJ(2, xj[2].x, xj[2].y);
    BODYJ(3, xj[3].x, xj[3].y);

    ep_base += 4096;
    xs += 2 * (size_t)BATCH;
  }

  // ---- epilogue: out = |v @ coreN| ----
  float cN[8][2];
#pragma unroll
  for (int t = 0; t < 8; ++t) {
    cN[t][0] = coreN[qmap(8 * g + t) * 2 + 0];
    cN[t][1] = coreN[qmap(8 * g + t) * 2 + 1];
  }
#pragma unroll
  for (int jj = 0; jj < NJ; ++jj) {
    float p0 = 0.f, p1 = 0.f;
#pragma unroll
    for (int t = 0; t < 8; ++t) {
      p0 += v[jj][t] * cN[t][0];
      p1 += v[jj][t] * cN[t][1];
    }
    p0 += __shfl_xor(p0, 16);
    p0 += __shfl_xor(p0, 32);
    p1 += __shfl_xor(p1, 16);
    p1 += __shfl_xor(p1, 32);
    if (g == 0) {
      const int a = abase + jj * 16 + col;
      out[2 * a] = fabsf(p0);
      out[2 * a + 1] = fabsf(p1);
    }
  }
}

extern "C" void kernel_launch(void* const* d_in, const int* in_sizes, int n_in,
                              void* d_out, int out_size, void* d_ws, size_t ws_size,
                              hipStream_t stream) {
  const float* X = (const float*)d_in[0];
  const float* core0 = (const float*)d_in[1];
  const float* cores = (const float*)d_in[2];
  const float* coreN = (const float*)d_in[3];
  float* out = (float*)d_out;
  unsigned short* Ep = (unsigned short*)d_ws;  // 258048 bytes

  hipLaunchKernelGGL(pack_E, dim3(((NSITES - 1) * 2048 + 255) / 256), dim3(256), 0, stream,
                     cores, Ep);
  hipLaunchKernelGGL(mps_chain_kernel, dim3(BATCH / BLOCK_BATCH), dim3(256), 0, stream, X,
                     core0, coreN, Ep, out);
}